// Round 2
// 705.723 us; speedup vs baseline: 1.0347x; 1.0347x over previous
//
#include <hip/hip_runtime.h>
#include <hip/hip_bf16.h>
#include <string.h>

#define B_ 256
#define L_ 512
#define H_ 768
#define K_ 64
#define WT_OFF 33554432   // emit = 131072*64*4 bytes, Wt after it

typedef float  float4v  __attribute__((ext_vector_type(4)));
typedef float  float2v  __attribute__((ext_vector_type(2)));
typedef short  short8v  __attribute__((ext_vector_type(8)));

union BFragU { uint4 u4; short8v s8; };

__device__ inline unsigned short f2bf_bits(float f) {
    union { float f; unsigned int u; } c; c.f = f;
    unsigned int u = c.u;
    u += 0x7fffu + ((u >> 16) & 1u);   // round-to-nearest-even
    return (unsigned short)(u >> 16);
}

__device__ inline float2v mk2(float x, float y) { float2v v; v.x = x; v.y = y; return v; }

// ---------------------------------------------------------------------------
// Kernel 0: Wt[k][h] = bf16(W[h][k])  (64 x 768 bf16 = 96 KB in d_ws)
// ---------------------------------------------------------------------------
__global__ void wt_transpose(const float* __restrict__ W, unsigned int* __restrict__ Wt) {
    int k = blockIdx.x;          // 0..63
    int j = threadIdx.x;         // 0..383, handles h = 2j, 2j+1
    float a = W[(size_t)(2 * j) * K_ + k];
    float b = W[(size_t)(2 * j + 1) * K_ + k];
    unsigned int u = (unsigned int)f2bf_bits(a) | ((unsigned int)f2bf_bits(b) << 16);
    Wt[k * (H_ / 2) + j] = u;
}

// ---------------------------------------------------------------------------
// Kernel 1: emit = features @ W + b.  64 rows/block (one 16-row MFMA tile per
// wave), 2048 blocks, 2-stage register pipeline.  Reg budget ~90 VGPR -> fits
// __launch_bounds__(256,3) (12 waves/CU) with no spill risk.  Mask skip at
// wave (16-row) granularity; mask is prefix-true per b and 16-row spans are
// t-aligned (never cross a b boundary).
// ---------------------------------------------------------------------------
struct StageS {
    uint4  b[4];
    float4 a[2];
};

__device__ __forceinline__ void load_stageS(StageS& s, const float* __restrict__ A,
        const unsigned short* __restrict__ Wt, int rowbase, int ks, int lm, int lq) {
    #pragma unroll
    for (int nt = 0; nt < 4; ++nt)
        s.b[nt] = *reinterpret_cast<const uint4*>(
            Wt + (size_t)(lm + nt * 16) * H_ + ks * 32 + lq * 8);
    const float* ap = A + (size_t)rowbase * H_ + ks * 32 + lq * 8;
    s.a[0] = *reinterpret_cast<const float4*>(ap);
    s.a[1] = *reinterpret_cast<const float4*>(ap + 4);
}

__device__ __forceinline__ void consume_stageS(const StageS& s, float4v acc[4]) {
    short8v bfrag[4];
    #pragma unroll
    for (int nt = 0; nt < 4; ++nt) { BFragU u; u.u4 = s.b[nt]; bfrag[nt] = u.s8; }
    __hip_bfloat162 tt[4];
    tt[0] = __float22bfloat162_rn(make_float2(s.a[0].x, s.a[0].y));
    tt[1] = __float22bfloat162_rn(make_float2(s.a[0].z, s.a[0].w));
    tt[2] = __float22bfloat162_rn(make_float2(s.a[1].x, s.a[1].y));
    tt[3] = __float22bfloat162_rn(make_float2(s.a[1].z, s.a[1].w));
    short8v afrag;
    memcpy(&afrag, tt, 16);
    #pragma unroll
    for (int nt = 0; nt < 4; ++nt)
        acc[nt] = __builtin_amdgcn_mfma_f32_16x16x32_bf16(afrag, bfrag[nt], acc[nt], 0, 0, 0);
}

__global__ __launch_bounds__(256, 3)
void emit_gemm(const float* __restrict__ A, const unsigned short* __restrict__ Wt,
               const float* __restrict__ bias, const int* __restrict__ mask,
               float* __restrict__ emit) {
    const int tid  = threadIdx.x;
    const int lane = tid & 63;
    const int wid  = tid >> 6;
    const int lm   = lane & 15;
    const int lq   = lane >> 4;
    const int r0   = blockIdx.x * 64;
    if (mask[r0 + wid * 16] == 0) return;
    const int rowbase = r0 + wid * 16 + lm;

    float4v acc[4];
    #pragma unroll
    for (int nt = 0; nt < 4; ++nt) acc[nt] = (float4v)0.f;

    StageS s0, s1;
    load_stageS(s0, A, Wt, rowbase, 0, lm, lq);
    #pragma unroll 1
    for (int ks = 0; ks < 24; ks += 2) {
        load_stageS(s1, A, Wt, rowbase, ks + 1, lm, lq);
        consume_stageS(s0, acc);
        load_stageS(s0, A, Wt, rowbase, (ks + 2 < 24) ? ks + 2 : 23, lm, lq);
        consume_stageS(s1, acc);
    }

    // epilogue: C/D map col=lane&15, row=(lane>>4)*4+r
    float bv[4];
    #pragma unroll
    for (int nt = 0; nt < 4; ++nt) bv[nt] = bias[nt * 16 + lm];
    const int rowb = r0 + wid * 16 + lq * 4;
    #pragma unroll
    for (int nt = 0; nt < 4; ++nt) {
        int col = nt * 16 + lm;
        #pragma unroll
        for (int r = 0; r < 4; ++r)
            emit[(size_t)(rowb + r) * K_ + col] = acc[nt][r] + bv[nt];
    }
}

// ---------------------------------------------------------------------------
// Kernel 2: CRF forward scan in shifted-exp space.
//  - emission e[t][lane] read straight from global (coalesced 256B/step)
//    through an 8-deep register prefetch ring (static indices, no scratch)
//    -> no ebuf LDS staging.
//  - eps refresh EVERY step (round-0 semantics).  Deferred refresh is exact
//    in real arithmetic but lets s accumulate 3 extra growth factors
//    (~2^30-45 in tails) -> fp32 overflow -> 0*inf NaN.  Per-step refresh
//    caps the range at one step's growth (~2^36 worst) as in round 0.
// ---------------------------------------------------------------------------
__global__ __launch_bounds__(64, 1)
void crf_scan(const float* __restrict__ emit, const float* __restrict__ T,
              const int* __restrict__ tags, const int* __restrict__ mask,
              float* __restrict__ out) {
    const int b    = blockIdx.x;
    const int lane = threadIdx.x;
    __shared__ __align__(16) float qbuf[2][64];

    int len = 0;
    #pragma unroll
    for (int j = 0; j < 8; ++j) len += (mask[b * L_ + j * 64 + lane] != 0);
    #pragma unroll
    for (int off = 32; off; off >>= 1) len += __shfl_xor(len, off, 64);

    float2v et2[32];
    #pragma unroll
    for (int j = 0; j < 32; ++j) {
        et2[j].x = __expf(T[(2 * j) * K_ + lane]);
        et2[j].y = __expf(T[(2 * j + 1) * K_ + lane]);
    }

    const float* eb = emit + (size_t)b * L_ * K_;

    float sc = 0.f;
    for (int tt = lane; tt < len; tt += 64) {
        int tg = tags[b * L_ + tt];
        sc += eb[(size_t)tt * K_ + tg];
        if (tt > 0) sc += T[tags[b * L_ + tt - 1] * K_ + tg];
    }
    #pragma unroll
    for (int off = 32; off; off >>= 1) sc += __shfl_xor(sc, off, 64);

    float e00 = eb[lane];
    float M = __int_as_float(__builtin_amdgcn_readfirstlane(__float_as_int(e00)));
    float q = __expf(e00 - M);
    qbuf[0][lane] = q;

    // prefetch e[1..8]; len >= 128 so these rows always exist and are written
    float eA[4], eB[4];
    #pragma unroll
    for (int i = 0; i < 4; ++i) {
        eA[i] = eb[(size_t)(1 + i) * K_ + lane];
        eB[i] = eb[(size_t)(5 + i) * K_ + lane];
    }

    int eps = 0;
    int t = 1;

    auto step = [&](float& ereg) {
        float e = ereg;
        int tp = t + 8; if (tp > L_ - 1) tp = L_ - 1;     // slot refill, 8 ahead
        ereg = eb[(size_t)tp * K_ + lane];
        float ef = __int_as_float(__builtin_amdgcn_readfirstlane(__float_as_int(e)));
        float delta = (float)eps * 0.69314718f + ef;
        M += delta;
        float f = __expf(e - delta);

        const float4* qb4 = reinterpret_cast<const float4*>(&qbuf[(t + 1) & 1][0]);
        float2v a0 = mk2(0.f, 0.f), a1 = mk2(0.f, 0.f);
        float2v a2 = mk2(0.f, 0.f), a3 = mk2(0.f, 0.f);
        #pragma unroll
        for (int r = 0; r < 16; r += 2) {
            float4 p0 = qb4[r];
            float4 p1 = qb4[r + 1];
            a0 += mk2(p0.x, p0.y) * et2[2 * r];
            a1 += mk2(p0.z, p0.w) * et2[2 * r + 1];
            a2 += mk2(p1.x, p1.y) * et2[2 * r + 2];
            a3 += mk2(p1.z, p1.w) * et2[2 * r + 3];
        }
        float2v s2 = (a0 + a1) + (a2 + a3);
        float s = s2.x + s2.y;
        unsigned su = (unsigned)__builtin_amdgcn_readfirstlane(__float_as_int(s));
        eps = (int)((su >> 23) & 0xffu) - 127;
        q = s * f;
        qbuf[t & 1][lane] = q;
        ++t;
    };

    #pragma unroll 1
    while (t < len) {
        step(eA[0]); if (t >= len) break;
        step(eA[1]); if (t >= len) break;
        step(eA[2]); if (t >= len) break;
        step(eA[3]); if (t >= len) break;
        step(eB[0]); if (t >= len) break;
        step(eB[1]); if (t >= len) break;
        step(eB[2]); if (t >= len) break;
        step(eB[3]);
    }

    float z = q;
    #pragma unroll
    for (int off = 32; off; off >>= 1) z += __shfl_xor(z, off, 64);
    if (lane == 0) out[b] = M + __logf(z) - sc;
}

extern "C" void kernel_launch(void* const* d_in, const int* in_sizes, int n_in,
                              void* d_out, int out_size, void* d_ws, size_t ws_size,
                              hipStream_t stream) {
    const float* feat = (const float*)d_in[0];
    const float* W    = (const float*)d_in[1];
    const float* bias = (const float*)d_in[2];
    const float* T    = (const float*)d_in[3];
    const int*   tags = (const int*)d_in[4];
    const int*   mask = (const int*)d_in[5];
    float* out  = (float*)d_out;
    float* emit = (float*)d_ws;                                   // 33.5 MB
    unsigned int*   WtW = (unsigned int*)((char*)d_ws + WT_OFF);  // 96 KB bf16
    unsigned short* Wt  = (unsigned short*)WtW;

    hipLaunchKernelGGL(wt_transpose, dim3(K_),   dim3(H_ / 2), 0, stream, W, WtW);
    hipLaunchKernelGGL(emit_gemm,    dim3(2048), dim3(256),    0, stream, feat, Wt, bias, mask, emit);
    hipLaunchKernelGGL(crf_scan,     dim3(B_),   dim3(64),     0, stream, emit, T, tags, mask, out);
}